// Round 1
// baseline (660.892 us; speedup 1.0000x reference)
//
#include <hip/hip_runtime.h>
#include <hip/hip_bf16.h>

#define B_  4
#define T_  2048
#define C_  1024
#define NH_ 16
#define D_  64
#define BH_ (B_*NH_)   // 64
#define M_  (B_*T_)    // 8192

typedef __attribute__((ext_vector_type(8))) short short8;
typedef __attribute__((ext_vector_type(4))) float f32x4;

__device__ __forceinline__ ushort f2bf(float f) {
    unsigned u = __float_as_uint(f);
    u += 0x7FFF + ((u >> 16) & 1);   // RNE
    return (ushort)(u >> 16);
}

// ---------------------------------------------------------------------------
// Generic 64x64-tile MFMA GEMM, BK=32, 4 waves (2x2), each wave 32x32.
// MODE 0: A = x (fp32, lda=K), B = W_attn (fp32) -> scatter epilogue to
//         Q [BH][T][D], K [BH][T][D], Vt [BH][D][T] (bf16) with fused biases.
// MODE 1: A = y (bf16, lda=K), B = W_proj (fp32) -> out fp32 (+ b_proj).
// ---------------------------------------------------------------------------
template<int MODE>
__global__ __launch_bounds__(256) void gemm_kernel(
    const void* __restrict__ Aptr, const float* __restrict__ Bptr,
    const float* __restrict__ b_attn, const float* __restrict__ bQ,
    const float* __restrict__ bK,
    ushort* __restrict__ Qb, ushort* __restrict__ Kb, ushort* __restrict__ Vt,
    float* __restrict__ outp, const float* __restrict__ b_proj,
    int K, int N)
{
    __shared__ ushort As[64][40];   // [m][k]  (pad 32->40, keeps 16B align)
    __shared__ ushort Bs[64][40];   // [n][k]  (B^T tile)

    const int tid  = threadIdx.x;
    const int lane = tid & 63;
    const int w    = tid >> 6;        // 0..3
    const int wr   = w >> 1, wc = w & 1;
    const int l16  = lane & 15;
    const int lg   = lane >> 4;       // 0..3
    const int m0   = blockIdx.x * 64;
    const int n0   = blockIdx.y * 64;

    // staging indices
    const int ar  = tid >> 2;          // 0..63
    const int akc = (tid & 3) * 8;     // 0,8,16,24
    const int bn  = tid & 63;          // 0..63 (col)
    const int bkc = (tid >> 6) * 8;    // 0,8,16,24

    f32x4 acc[2][2] = {};

    for (int k0 = 0; k0 < K; k0 += 32) {
        // ---- stage A tile ----
        if constexpr (MODE == 0) {
            const float* src = (const float*)Aptr + (size_t)(m0 + ar) * K + k0 + akc;
            f32x4 v0 = *(const f32x4*)src;
            f32x4 v1 = *(const f32x4*)(src + 4);
            union { short8 v; ushort u[8]; } pk;
            #pragma unroll
            for (int j = 0; j < 4; ++j) { pk.u[j] = f2bf(v0[j]); pk.u[4+j] = f2bf(v1[j]); }
            *(short8*)&As[ar][akc] = pk.v;
        } else {
            const ushort* src = (const ushort*)Aptr + (size_t)(m0 + ar) * K + k0 + akc;
            *(short8*)&As[ar][akc] = *(const short8*)src;
        }
        // ---- stage B tile (transposed: Bs[n][k]) ----
        {
            const float* bsrc = Bptr + (size_t)(k0 + bkc) * N + n0 + bn;
            union { short8 v; ushort u[8]; } pb;
            #pragma unroll
            for (int j = 0; j < 8; ++j) pb.u[j] = f2bf(bsrc[(size_t)j * N]);
            *(short8*)&Bs[bn][bkc] = pb.v;
        }
        __syncthreads();

        short8 a0 = *(const short8*)&As[wr*32 +  0 + l16][lg*8];
        short8 a1 = *(const short8*)&As[wr*32 + 16 + l16][lg*8];
        short8 b0 = *(const short8*)&Bs[wc*32 +  0 + l16][lg*8];
        short8 b1 = *(const short8*)&Bs[wc*32 + 16 + l16][lg*8];

        acc[0][0] = __builtin_amdgcn_mfma_f32_16x16x32_bf16(a0, b0, acc[0][0], 0, 0, 0);
        acc[0][1] = __builtin_amdgcn_mfma_f32_16x16x32_bf16(a0, b1, acc[0][1], 0, 0, 0);
        acc[1][0] = __builtin_amdgcn_mfma_f32_16x16x32_bf16(a1, b0, acc[1][0], 0, 0, 0);
        acc[1][1] = __builtin_amdgcn_mfma_f32_16x16x32_bf16(a1, b1, acc[1][1], 0, 0, 0);
        __syncthreads();
    }

    // ---- epilogue ----
    #pragma unroll
    for (int rb = 0; rb < 2; ++rb) {
        #pragma unroll
        for (int cb = 0; cb < 2; ++cb) {
            const int n = n0 + wc*32 + cb*16 + l16;
            if constexpr (MODE == 0) {
                const int sec = n >> 10;      // 0=Q 1=K 2=V
                const int nn  = n & 1023;     // = h*64 + d
                const int h = nn >> 6, d = nn & 63;
                const float ba = b_attn[n];
                #pragma unroll
                for (int r = 0; r < 4; ++r) {
                    const int m = m0 + wr*32 + rb*16 + lg*4 + r;
                    const int b = m >> 11, t = m & 2047;
                    float v = acc[rb][cb][r] + ba;
                    if (sec == 0) {
                        v += bQ[nn];
                        Qb[((size_t)(b*NH_ + h)*T_ + t)*D_ + d] = f2bf(v);
                    } else if (sec == 1) {
                        v += bK[nn];
                        Kb[((size_t)(b*NH_ + h)*T_ + t)*D_ + d] = f2bf(v);
                    } else {
                        Vt[((size_t)(b*NH_ + h)*D_ + d)*T_ + t] = f2bf(v);
                    }
                }
            } else {
                const float bp = b_proj[n];
                #pragma unroll
                for (int r = 0; r < 4; ++r) {
                    const int m = m0 + wr*32 + rb*16 + lg*4 + r;
                    outp[(size_t)m * N + n] = acc[rb][cb][r] + bp;
                }
            }
        }
    }
}

// ---------------------------------------------------------------------------
// Flash attention: block = 4 waves, each wave owns 16 q-rows of one (b,h).
// KT=32 per iteration. No block-wide barriers in the loop (waves diverge in
// trip count); P transpose goes through wave-private LDS.
// ---------------------------------------------------------------------------
__global__ __launch_bounds__(256) void attn_kernel(
    const ushort* __restrict__ Qb, const ushort* __restrict__ Kb,
    const ushort* __restrict__ Vt, ushort* __restrict__ y)
{
    __shared__ ushort P_lds[4][16][40];

    const int tid  = threadIdx.x;
    const int lane = tid & 63;
    const int w    = tid >> 6;
    const int l16  = lane & 15;
    const int lg   = lane >> 4;
    const int qt   = blockIdx.x;          // 0..31
    const int bh   = blockIdx.y;          // 0..63
    const int b    = bh >> 4, h = bh & 15;
    const int q0   = qt * 64 + w * 16;

    // Q fragments (held in regs for whole kernel)
    const ushort* Qrow = Qb + ((size_t)bh * T_ + q0 + l16) * D_;
    const short8 aq0 = *(const short8*)(Qrow + 0  + lg*8);
    const short8 aq1 = *(const short8*)(Qrow + 32 + lg*8);

    float mrow[4], lrow[4];
    f32x4 o[4] = {};
    #pragma unroll
    for (int r = 0; r < 4; ++r) { mrow[r] = -__builtin_inff(); lrow[r] = 0.f; }

    const float sc2 = 0.125f * 1.44269504088896340736f;  // (1/sqrt(D))*log2(e)

    const int ntiles = (q0 + 16 + 31) >> 5;
    for (int kt = 0; kt < ntiles; ++kt) {
        const int kbase = kt * 32;

        // ---- S = Q K^T (16x32) ----
        f32x4 s[2] = {};
        #pragma unroll
        for (int cg = 0; cg < 2; ++cg) {
            const ushort* Krow = Kb + ((size_t)bh*T_ + kbase + cg*16 + l16) * D_;
            const short8 bk0 = *(const short8*)(Krow + 0  + lg*8);
            const short8 bk1 = *(const short8*)(Krow + 32 + lg*8);
            s[cg] = __builtin_amdgcn_mfma_f32_16x16x32_bf16(aq0, bk0, s[cg], 0, 0, 0);
            s[cg] = __builtin_amdgcn_mfma_f32_16x16x32_bf16(aq1, bk1, s[cg], 0, 0, 0);
        }

        // ---- scale + causal mask + online softmax ----
        float pv[2][4], vmax[4];
        #pragma unroll
        for (int r = 0; r < 4; ++r) {
            const int q = q0 + lg*4 + r;
            float x0 = (kbase +  0 + l16 <= q) ? s[0][r]*sc2 : -__builtin_inff();
            float x1 = (kbase + 16 + l16 <= q) ? s[1][r]*sc2 : -__builtin_inff();
            pv[0][r] = x0; pv[1][r] = x1;
            vmax[r] = fmaxf(x0, x1);
        }
        #pragma unroll
        for (int mk = 1; mk < 16; mk <<= 1) {
            #pragma unroll
            for (int r = 0; r < 4; ++r)
                vmax[r] = fmaxf(vmax[r], __shfl_xor(vmax[r], mk, 64));
        }
        float alpha[4], rsum[4];
        #pragma unroll
        for (int r = 0; r < 4; ++r) {
            const float mn = fmaxf(mrow[r], vmax[r]);
            alpha[r] = exp2f(mrow[r] - mn);   // m_old=-inf -> 0
            mrow[r] = mn;
            const float p0 = exp2f(pv[0][r] - mn);
            const float p1 = exp2f(pv[1][r] - mn);
            pv[0][r] = p0; pv[1][r] = p1;
            rsum[r] = p0 + p1;
        }
        #pragma unroll
        for (int mk = 1; mk < 16; mk <<= 1) {
            #pragma unroll
            for (int r = 0; r < 4; ++r)
                rsum[r] += __shfl_xor(rsum[r], mk, 64);
        }
        #pragma unroll
        for (int r = 0; r < 4; ++r) lrow[r] = lrow[r]*alpha[r] + rsum[r];
        #pragma unroll
        for (int cb = 0; cb < 4; ++cb)
            #pragma unroll
            for (int r = 0; r < 4; ++r) o[cb][r] *= alpha[r];

        // ---- P: C-layout -> A-layout via wave-private LDS ----
        #pragma unroll
        for (int cg = 0; cg < 2; ++cg)
            #pragma unroll
            for (int r = 0; r < 4; ++r)
                P_lds[w][lg*4 + r][cg*16 + l16] = f2bf(pv[cg][r]);

        const short8 pa = *(const short8*)&P_lds[w][l16][lg*8];

        // ---- O += P V ----
        #pragma unroll
        for (int cb = 0; cb < 4; ++cb) {
            const ushort* Vrow = Vt + ((size_t)bh*D_ + cb*16 + l16) * T_ + kbase + lg*8;
            const short8 bv = *(const short8*)Vrow;
            o[cb] = __builtin_amdgcn_mfma_f32_16x16x32_bf16(pa, bv, o[cb], 0, 0, 0);
        }
    }

    // ---- normalize + store y (bf16, [B][T][C] layout) ----
    #pragma unroll
    for (int r = 0; r < 4; ++r) {
        const float inv = 1.0f / lrow[r];
        const int q = q0 + lg*4 + r;
        ushort* yrow = y + ((size_t)b*T_ + q)*C_ + h*D_;
        #pragma unroll
        for (int cb = 0; cb < 4; ++cb)
            yrow[cb*16 + l16] = f2bf(o[cb][r] * inv);
    }
}

__global__ void copy_bq_kernel(const float* __restrict__ bQ, float* __restrict__ dst) {
    const int i = blockIdx.x * 256 + threadIdx.x;
    if (i < NH_ * D_) dst[i] = bQ[i];
}

extern "C" void kernel_launch(void* const* d_in, const int* in_sizes, int n_in,
                              void* d_out, int out_size, void* d_ws, size_t ws_size,
                              hipStream_t stream)
{
    const float* x      = (const float*)d_in[0];
    const float* W_attn = (const float*)d_in[1];
    const float* b_attn = (const float*)d_in[2];
    const float* W_proj = (const float*)d_in[3];
    const float* b_proj = (const float*)d_in[4];
    const float* bQ     = (const float*)d_in[5];
    const float* bK     = (const float*)d_in[6];
    float* out = (float*)d_out;

    const size_t HE = (size_t)BH_ * T_ * D_;   // 8M elems
    ushort* Qb = (ushort*)d_ws;
    ushort* Kb = Qb + HE;
    ushort* Vt = Kb + HE;
    ushort* y  = Vt + HE;                       // [B][T][C] bf16

    // 1) QKV GEMM + bias + scatter (M=8192, N=3072, K=1024)
    gemm_kernel<0><<<dim3(M_/64, 3*C_/64), 256, 0, stream>>>(
        x, W_attn, b_attn, bQ, bK, Qb, Kb, Vt, nullptr, nullptr, C_, 3*C_);

    // 2) causal flash attention
    attn_kernel<<<dim3(T_/64, BH_), 256, 0, stream>>>(Qb, Kb, Vt, y);

    // 3) out = y @ W_proj + b_proj  (M=8192, N=1024, K=1024)
    gemm_kernel<1><<<dim3(M_/64, C_/64), 256, 0, stream>>>(
        y, W_proj, nullptr, nullptr, nullptr, nullptr, nullptr, nullptr,
        out, b_proj, C_, C_);

    // 4) second tuple element: bQ passthrough
    copy_bq_kernel<<<(NH_*D_ + 255)/256, 256, 0, stream>>>(
        bQ, out + (size_t)M_ * C_);
}

// Round 2
// 415.272 us; speedup vs baseline: 1.5915x; 1.5915x over previous
//
#include <hip/hip_runtime.h>
#include <hip/hip_bf16.h>

#define B_  4
#define T_  2048
#define C_  1024
#define NH_ 16
#define D_  64
#define BH_ (B_*NH_)   // 64
#define M_  (B_*T_)    // 8192

typedef __attribute__((ext_vector_type(8))) short short8;
typedef __attribute__((ext_vector_type(4))) short short4v;
typedef __attribute__((ext_vector_type(4))) float f32x4;

__device__ __forceinline__ ushort f2bf(float f) {
    unsigned u = __float_as_uint(f);
    u += 0x7FFF + ((u >> 16) & 1);   // RNE
    return (ushort)(u >> 16);
}

// ---------------------------------------------------------------------------
// Generic 64x64-tile MFMA GEMM, BK=32, 4 waves (2x2), each wave 32x32.
// MODE 0: A = x (fp32), B = W_attn (fp32) -> scatter to Q/K [BH][T][D],
//         Vt [BH][D][T] (bf16) with fused biases.
// MODE 1: A = y (bf16), B = W_proj (fp32) -> out fp32 (+ b_proj).
// ---------------------------------------------------------------------------
template<int MODE>
__global__ __launch_bounds__(256) void gemm_kernel(
    const void* __restrict__ Aptr, const float* __restrict__ Bptr,
    const float* __restrict__ b_attn, const float* __restrict__ bQ,
    const float* __restrict__ bK,
    ushort* __restrict__ Qb, ushort* __restrict__ Kb, ushort* __restrict__ Vt,
    float* __restrict__ outp, const float* __restrict__ b_proj,
    int K, int N)
{
    __shared__ ushort As[64][40];
    __shared__ ushort Bs[64][40];

    const int tid  = threadIdx.x;
    const int lane = tid & 63;
    const int w    = tid >> 6;
    const int wr   = w >> 1, wc = w & 1;
    const int l16  = lane & 15;
    const int lg   = lane >> 4;
    const int m0   = blockIdx.x * 64;
    const int n0   = blockIdx.y * 64;

    const int ar  = tid >> 2;
    const int akc = (tid & 3) * 8;
    const int bn  = tid & 63;
    const int bkc = (tid >> 6) * 8;

    f32x4 acc[2][2] = {};

    for (int k0 = 0; k0 < K; k0 += 32) {
        if constexpr (MODE == 0) {
            const float* src = (const float*)Aptr + (size_t)(m0 + ar) * K + k0 + akc;
            f32x4 v0 = *(const f32x4*)src;
            f32x4 v1 = *(const f32x4*)(src + 4);
            union { short8 v; ushort u[8]; } pk;
            #pragma unroll
            for (int j = 0; j < 4; ++j) { pk.u[j] = f2bf(v0[j]); pk.u[4+j] = f2bf(v1[j]); }
            *(short8*)&As[ar][akc] = pk.v;
        } else {
            const ushort* src = (const ushort*)Aptr + (size_t)(m0 + ar) * K + k0 + akc;
            *(short8*)&As[ar][akc] = *(const short8*)src;
        }
        {
            const float* bsrc = Bptr + (size_t)(k0 + bkc) * N + n0 + bn;
            union { short8 v; ushort u[8]; } pb;
            #pragma unroll
            for (int j = 0; j < 8; ++j) pb.u[j] = f2bf(bsrc[(size_t)j * N]);
            *(short8*)&Bs[bn][bkc] = pb.v;
        }
        __syncthreads();

        short8 a0 = *(const short8*)&As[wr*32 +  0 + l16][lg*8];
        short8 a1 = *(const short8*)&As[wr*32 + 16 + l16][lg*8];
        short8 b0 = *(const short8*)&Bs[wc*32 +  0 + l16][lg*8];
        short8 b1 = *(const short8*)&Bs[wc*32 + 16 + l16][lg*8];

        acc[0][0] = __builtin_amdgcn_mfma_f32_16x16x32_bf16(a0, b0, acc[0][0], 0, 0, 0);
        acc[0][1] = __builtin_amdgcn_mfma_f32_16x16x32_bf16(a0, b1, acc[0][1], 0, 0, 0);
        acc[1][0] = __builtin_amdgcn_mfma_f32_16x16x32_bf16(a1, b0, acc[1][0], 0, 0, 0);
        acc[1][1] = __builtin_amdgcn_mfma_f32_16x16x32_bf16(a1, b1, acc[1][1], 0, 0, 0);
        __syncthreads();
    }

    #pragma unroll
    for (int rb = 0; rb < 2; ++rb) {
        #pragma unroll
        for (int cb = 0; cb < 2; ++cb) {
            const int n = n0 + wc*32 + cb*16 + l16;
            if constexpr (MODE == 0) {
                const int sec = n >> 10;
                const int nn  = n & 1023;
                const int h = nn >> 6, d = nn & 63;
                const float ba = b_attn[n];
                #pragma unroll
                for (int r = 0; r < 4; ++r) {
                    const int m = m0 + wr*32 + rb*16 + lg*4 + r;
                    const int b = m >> 11, t = m & 2047;
                    float v = acc[rb][cb][r] + ba;
                    if (sec == 0) {
                        v += bQ[nn];
                        Qb[((size_t)(b*NH_ + h)*T_ + t)*D_ + d] = f2bf(v);
                    } else if (sec == 1) {
                        v += bK[nn];
                        Kb[((size_t)(b*NH_ + h)*T_ + t)*D_ + d] = f2bf(v);
                    } else {
                        Vt[((size_t)(b*NH_ + h)*D_ + d)*T_ + t] = f2bf(v);
                    }
                }
            } else {
                const float bp = b_proj[n];
                #pragma unroll
                for (int r = 0; r < 4; ++r) {
                    const int m = m0 + wr*32 + rb*16 + lg*4 + r;
                    outp[(size_t)m * N + n] = acc[rb][cb][r] + bp;
                }
            }
        }
    }
}

// ---------------------------------------------------------------------------
// Flash attention, swapped-operand form. No LDS, no barriers.
// Each wave: 32 queries (two 16-col groups), 64-key tiles.
// S^T = mfma(K_rows, Q_rows); P stays in-register; PV uses a matched
// k-slot permutation so P's C-layout IS the B-fragment; O kept as O^T.
// Block processes q-super-tile pair {p, 15-p} for load balance.
// ---------------------------------------------------------------------------
__global__ __launch_bounds__(256, 3) void attn_kernel(
    const ushort* __restrict__ Qb, const ushort* __restrict__ Kb,
    const ushort* __restrict__ Vt, ushort* __restrict__ y)
{
    const int tid  = threadIdx.x;
    const int lane = tid & 63;
    const int w    = tid >> 6;
    const int l16  = lane & 15;
    const int lg   = lane >> 4;
    const int bh   = blockIdx.y;
    const int b    = bh >> 4, h = bh & 15;
    const size_t kvbase = (size_t)bh * T_ * D_;
    const size_t vtbase = (size_t)bh * D_ * T_;

    const float sc2 = 0.125f * 1.44269504088896340736f;  // (1/sqrt(D))*log2(e)

    #pragma unroll 1
    for (int pi = 0; pi < 2; ++pi) {
        const int pass = (pi == 0) ? (int)blockIdx.x : (15 - (int)blockIdx.x);
        const int qb = pass * 128 + w * 32;

        // Q fragments (B-slot): lane holds Q[qb+g*16+l16][c*32+lg*8 .. +7]
        short8 qf[2][2];
        #pragma unroll
        for (int g = 0; g < 2; ++g)
            #pragma unroll
            for (int c = 0; c < 2; ++c)
                qf[g][c] = *(const short8*)(Qb + kvbase +
                            (size_t)(qb + g*16 + l16)*D_ + c*32 + lg*8);

        f32x4 o[2][4] = {};
        float mrow[2] = {-1e30f, -1e30f};
        float lrow[2] = {0.f, 0.f};

        const int ntiles = (qb + 95) >> 6;
        for (int kt = 0; kt < ntiles; ++kt) {
            const int kb = kt * 64;

            // ---- S^T = K · Q^T  (64 keys x 32 queries) ----
            f32x4 s[2][4];
            #pragma unroll
            for (int g = 0; g < 2; ++g)
                #pragma unroll
                for (int t = 0; t < 4; ++t)
                    s[g][t] = (f32x4){0.f, 0.f, 0.f, 0.f};
            #pragma unroll
            for (int t = 0; t < 4; ++t) {
                const ushort* kr = Kb + kvbase + (size_t)(kb + t*16 + l16)*D_ + lg*8;
                const short8 k0 = *(const short8*)kr;          // d 0..31 slice
                const short8 k1 = *(const short8*)(kr + 32);   // d 32..63 slice
                s[0][t] = __builtin_amdgcn_mfma_f32_16x16x32_bf16(k0, qf[0][0], s[0][t], 0, 0, 0);
                s[0][t] = __builtin_amdgcn_mfma_f32_16x16x32_bf16(k1, qf[0][1], s[0][t], 0, 0, 0);
                s[1][t] = __builtin_amdgcn_mfma_f32_16x16x32_bf16(k0, qf[1][0], s[1][t], 0, 0, 0);
                s[1][t] = __builtin_amdgcn_mfma_f32_16x16x32_bf16(k1, qf[1][1], s[1][t], 0, 0, 0);
            }

            // ---- online softmax per query group (lane's q = l16) ----
            short8 pb[2][2];
            #pragma unroll
            for (int g = 0; g < 2; ++g) {
                const int q = qb + g*16 + l16;
                const bool full = (kb + 63 <= qb + g*16);   // wave-uniform
                float x[4][4];
                #pragma unroll
                for (int t = 0; t < 4; ++t)
                    #pragma unroll
                    for (int r = 0; r < 4; ++r) {
                        float v = s[g][t][r] * sc2;
                        if (!full)
                            v = (kb + t*16 + lg*4 + r <= q) ? v : -1e30f;
                        x[t][r] = v;
                    }
                float vm = x[0][0];
                #pragma unroll
                for (int t = 0; t < 4; ++t)
                    #pragma unroll
                    for (int r = 0; r < 4; ++r)
                        vm = fmaxf(vm, x[t][r]);
                vm = fmaxf(vm, __shfl_xor(vm, 16, 64));
                vm = fmaxf(vm, __shfl_xor(vm, 32, 64));
                const float mn    = fmaxf(mrow[g], vm);
                const float alpha = __builtin_amdgcn_exp2f(mrow[g] - mn);
                mrow[g] = mn;
                float rs = 0.f;
                #pragma unroll
                for (int t = 0; t < 4; ++t)
                    #pragma unroll
                    for (int r = 0; r < 4; ++r) {
                        const float p = __builtin_amdgcn_exp2f(x[t][r] - mn);
                        x[t][r] = p;
                        rs += p;
                    }
                rs += __shfl_xor(rs, 16, 64);
                rs += __shfl_xor(rs, 32, 64);
                lrow[g] = lrow[g]*alpha + rs;
                #pragma unroll
                for (int cb = 0; cb < 4; ++cb)
                    #pragma unroll
                    for (int r = 0; r < 4; ++r)
                        o[g][cb][r] *= alpha;
                // pack P into PV B-fragments: sigma(lg*8+j) = (j>>2)*16+lg*4+(j&3)
                #pragma unroll
                for (int kc = 0; kc < 2; ++kc) {
                    union { short8 v; ushort u[8]; } pk;
                    #pragma unroll
                    for (int j = 0; j < 8; ++j)
                        pk.u[j] = f2bf(x[kc*2 + (j>>2)][j&3]);
                    pb[g][kc] = pk.v;
                }
            }

            // ---- O^T += V^T · P^T  (A = V^T rows with matching sigma) ----
            #pragma unroll
            for (int cb = 0; cb < 4; ++cb) {
                const ushort* vr = Vt + vtbase + (size_t)(cb*16 + l16)*T_ + kb + lg*4;
                union { short8 v; short4v h[2]; } va0, va1;
                va0.h[0] = *(const short4v*)vr;
                va0.h[1] = *(const short4v*)(vr + 16);
                va1.h[0] = *(const short4v*)(vr + 32);
                va1.h[1] = *(const short4v*)(vr + 48);
                o[0][cb] = __builtin_amdgcn_mfma_f32_16x16x32_bf16(va0.v, pb[0][0], o[0][cb], 0, 0, 0);
                o[0][cb] = __builtin_amdgcn_mfma_f32_16x16x32_bf16(va1.v, pb[0][1], o[0][cb], 0, 0, 0);
                o[1][cb] = __builtin_amdgcn_mfma_f32_16x16x32_bf16(va0.v, pb[1][0], o[1][cb], 0, 0, 0);
                o[1][cb] = __builtin_amdgcn_mfma_f32_16x16x32_bf16(va1.v, pb[1][1], o[1][cb], 0, 0, 0);
            }
        }

        // ---- normalize + store y (bf16, [B][T][C]) ----
        #pragma unroll
        for (int g = 0; g < 2; ++g) {
            const float inv = 1.0f / lrow[g];
            const int q = qb + g*16 + l16;
            ushort* yr = y + ((size_t)b*T_ + q)*C_ + h*D_ + lg*4;
            #pragma unroll
            for (int cb = 0; cb < 4; ++cb) {
                union { short4v v; ushort u[4]; } st;
                #pragma unroll
                for (int r = 0; r < 4; ++r)
                    st.u[r] = f2bf(o[g][cb][r] * inv);
                *(short4v*)(yr + cb*16) = st.v;
            }
        }
    }
}

__global__ void copy_bq_kernel(const float* __restrict__ bQ, float* __restrict__ dst) {
    const int i = blockIdx.x * 256 + threadIdx.x;
    if (i < NH_ * D_) dst[i] = bQ[i];
}

extern "C" void kernel_launch(void* const* d_in, const int* in_sizes, int n_in,
                              void* d_out, int out_size, void* d_ws, size_t ws_size,
                              hipStream_t stream)
{
    const float* x      = (const float*)d_in[0];
    const float* W_attn = (const float*)d_in[1];
    const float* b_attn = (const float*)d_in[2];
    const float* W_proj = (const float*)d_in[3];
    const float* b_proj = (const float*)d_in[4];
    const float* bQ     = (const float*)d_in[5];
    const float* bK     = (const float*)d_in[6];
    float* out = (float*)d_out;

    const size_t HE = (size_t)BH_ * T_ * D_;
    ushort* Qb = (ushort*)d_ws;
    ushort* Kb = Qb + HE;
    ushort* Vt = Kb + HE;
    ushort* y  = Vt + HE;

    gemm_kernel<0><<<dim3(M_/64, 3*C_/64), 256, 0, stream>>>(
        x, W_attn, b_attn, bQ, bK, Qb, Kb, Vt, nullptr, nullptr, C_, 3*C_);

    attn_kernel<<<dim3(8, BH_), 256, 0, stream>>>(Qb, Kb, Vt, y);

    gemm_kernel<1><<<dim3(M_/64, C_/64), 256, 0, stream>>>(
        y, W_proj, nullptr, nullptr, nullptr, nullptr, nullptr, nullptr,
        out, b_proj, C_, C_);

    copy_bq_kernel<<<(NH_*D_ + 255)/256, 256, 0, stream>>>(
        bQ, out + (size_t)M_ * C_);
}